// Round 5
// baseline (644.434 us; speedup 1.0000x reference)
//
#include <hip/hip_runtime.h>

// SplitConvStack: 3x depthwise dilated conv1d along W + ReLU, fused.
// x: [B=16, H=21, W=4096, C=64] fp32 NHWC; w1/w2/w3: [1,8,1,64].
// Stage dilations 1,2,4; SAME padding -> pad_lo = 3, 7, 14.
//
// One wave (64 lanes = 64 channels) streams a 256-wide W-chunk of one (b,h)
// row through a register software pipeline:
//   step t: load x[t+8] -> xf ; s1[t-4] from xf ; s2[t-11] from s1f ;
//           s3[t-25] from s2f -> store.
// FIFO sizes 16/16/32 divide the 32-step unrolled group and chunk bases are
// multiples of 32, so every FIFO index is a compile-time constant.
//
// ROUND 4 resubmit (infra failure, no kernel signal — same as Round 1).
// TLP fix: rounds 0-3 showed VALU instr count fell 2.5x while duration was
// flat -> latency-bound, not issue- or BW-bound. 256-thread blocks with
// launch_bounds(256,4) quantized residency to 4 blocks/CU (~9 waves).
// This round: identical r2 interior (verified 242 us, VGPR 60) but ONE WAVE
// PER BLOCK (64 threads, 5376 blocks). No LDS/syncthreads, so 1-wave blocks
// cost nothing and the whole grid (5.25 waves/SIMD avg) can be resident,
// ~2.5x-ing outstanding loads per CU. launch_bounds(64,4): VGPR cap 128,
// measured use is 60, so residency is capacity-limited (8/SIMD), not
// compiler-limited.

#define W_DIM   4096
#define C_DIM   64
#define L_CHUNK 256
#define NCHUNK  16      // W / L_CHUNK
#define NROWS   336     // B*H = 16*21

// ---- FMA bodies (no bounds predicates; FIFO indices fold after unroll) ----
#define S1_BODY(j) do {                                                     \
    float a_ = 0.f;                                                         \
    _Pragma("unroll")                                                       \
    for (int k = 0; k < 8; ++k)                                             \
        a_ = fmaf(xf[((j) - 7 + k + 32) & 15], w1r[k], a_);                 \
    s1f[((j) - 4 + 32) & 15] = fmaxf(a_, 0.f);                              \
} while (0)

#define S2_BODY(j) do {                                                     \
    float a_ = 0.f;                                                         \
    _Pragma("unroll")                                                       \
    for (int k = 0; k < 8; ++k)                                             \
        a_ = fmaf(s1f[((j) - 18 + 2 * k + 32) & 15], w2r[k], a_);           \
    s2f[((j) - 11 + 32) & 31] = fmaxf(a_, 0.f);                             \
} while (0)

#define S3_STORE(j, dst) do {                                               \
    float a_ = 0.f;                                                         \
    _Pragma("unroll")                                                       \
    for (int k = 0; k < 8; ++k)                                             \
        a_ = fmaf(s2f[((j) - 39 + 4 * k + 64) & 31], w3r[k], a_);           \
    (dst) = fmaxf(a_, 0.f);                                                 \
} while (0)

__global__ __launch_bounds__(64, 4)
void splitconv_fused_kernel(const float* __restrict__ x,
                            const float* __restrict__ w1,
                            const float* __restrict__ w2,
                            const float* __restrict__ w3,
                            float* __restrict__ out) {
    const int lane  = threadIdx.x & 63;               // channel
    // block b: chunk = b & 15 (wave-uniform), row = b >> 4 in [0,336).
    const int chunk = blockIdx.x & (NCHUNK - 1);
    const int row   = blockIdx.x >> 4;
    const int w0    = chunk * L_CHUNK;                // multiple of 256
    const int c     = lane;

    const float* __restrict__ xrow = x   + (size_t)row * (W_DIM * C_DIM) + c;
    float* __restrict__       orow = out + (size_t)row * (W_DIM * C_DIM) + c;

    // per-lane weights: w[k*C + c]
    float w1r[8], w2r[8], w3r[8];
#pragma unroll
    for (int k = 0; k < 8; ++k) {
        w1r[k] = w1[k * C_DIM + c];
        w2r[k] = w2[k * C_DIM + c];
        w3r[k] = w3[k * C_DIM + c];
    }

    float xf[16], s1f[16], s2f[32];
#pragma unroll
    for (int i = 0; i < 16; ++i) { xf[i] = 0.f; s1f[i] = 0.f; }
#pragma unroll
    for (int i = 0; i < 32; ++i) s2f[i] = 0.f;

    if (chunk >= 1 && chunk <= 14) {
        // ================= interior: zero runtime predicates =================
        // z(g,j) = w0 - 24 + 32g + j ; all z in [w0-24, w0+280] subset [0,W).
        const float* __restrict__ xp = xrow + (size_t)(w0 - 24) * C_DIM;
        float* __restrict__       op = orow + (size_t)w0 * C_DIM;

        // ---- g = 0: warm-up. s1 needed from v >= w0-21 (j>=15),
        //      s2 needed from u >= w0-14 (j>=29), no stores. ----
#pragma unroll
        for (int j = 0; j < 32; ++j) {
            xf[(j + 8) & 15] = xp[j * C_DIM];
            if (j >= 15) S1_BODY(j);
            if (j >= 29) S2_BODY(j);
        }
        xp += 32 * C_DIM;

        // ---- g = 1: full s1/s2; stores start at wq = w0 (j>=25). ----
#pragma unroll
        for (int j = 0; j < 32; ++j) {
            xf[(j + 8) & 15] = xp[j * C_DIM];
            S1_BODY(j);
            S2_BODY(j);
            if (j >= 25) S3_STORE(j, op[(j - 25) * C_DIM]);
        }
        xp += 32 * C_DIM;
        op += 7 * C_DIM;   // next store: g=2,j=0 -> rel 32*1 + 0 - 25 = 7

        // ---- g = 2..8: steady state, predicate-free. ----
#pragma unroll 1
        for (int g = 2; g <= 8; ++g) {
#pragma unroll
            for (int j = 0; j < 32; ++j) {
                xf[(j + 8) & 15] = xp[j * C_DIM];
                S1_BODY(j);
                S2_BODY(j);
                S3_STORE(j, op[j * C_DIM]);
            }
            xp += 32 * C_DIM;
            op += 32 * C_DIM;
        }

        // ---- g = 9: drain. loads needed through z = w0+280 (j<=16);
        //      s1/s2 through j<=24; stores through wq = w0+255 (j<25). ----
#pragma unroll
        for (int j = 0; j < 32; ++j) {
            if (j <= 16) xf[(j + 8) & 15] = xp[j * C_DIM];
            if (j <= 24) { S1_BODY(j); S2_BODY(j); }
            if (j <  25) S3_STORE(j, op[j * C_DIM]);
        }
    } else {
        // ================= edge chunks 0 and 15: generic path =================
        for (int g = 0; g < 10; ++g) {
            const int tbase = w0 - 32 + g * 32;       // == 0 (mod 32)
#pragma unroll
            for (int j = 0; j < 32; ++j) {
                const int t = tbase + j;              // t == j (mod 32)

                // ---- prefetch x[t+8] into xf[(t+8) % 16] ----
                {
                    const int z = t + 8;
                    float xv = 0.f;
                    if (z >= 0 && z < W_DIM && (z - w0) <= L_CHUNK + 24)
                        xv = xrow[(size_t)z * C_DIM];
                    xf[(j + 8) & 15] = xv;
                }

                // ---- stage 1 (d=1): s1[v], v = t-4 ----
                {
                    const int v = t - 4;
                    float a = 0.f;
#pragma unroll
                    for (int k = 0; k < 8; ++k)
                        a = fmaf(xf[(j - 7 + k + 32) & 15], w1r[k], a);
                    float s = fmaxf(a, 0.f);
                    s1f[(j - 4 + 32) & 15] = (v >= 0 && v < W_DIM) ? s : 0.f;
                }

                // ---- stage 2 (d=2): s2[u], u = t-11 ----
                {
                    const int u = t - 11;
                    float a = 0.f;
#pragma unroll
                    for (int k = 0; k < 8; ++k)
                        a = fmaf(s1f[(j - 18 + 2 * k + 32) & 15], w2r[k], a);
                    float s = fmaxf(a, 0.f);
                    s2f[(j - 11 + 32) & 31] = (u >= 0 && u < W_DIM) ? s : 0.f;
                }

                // ---- stage 3 (d=4): y[wq], wq = t-25 ----
                {
                    const int wq = t - 25;
                    if (wq >= w0 && wq < w0 + L_CHUNK) {
                        float a = 0.f;
#pragma unroll
                        for (int k = 0; k < 8; ++k)
                            a = fmaf(s2f[(j - 39 + 4 * k + 64) & 31], w3r[k], a);
                        orow[(size_t)wq * C_DIM] = fmaxf(a, 0.f);
                    }
                }
            }
        }
    }
}

extern "C" void kernel_launch(void* const* d_in, const int* in_sizes, int n_in,
                              void* d_out, int out_size, void* d_ws, size_t ws_size,
                              hipStream_t stream) {
    const float* x  = (const float*)d_in[0];
    const float* w1 = (const float*)d_in[1];
    const float* w2 = (const float*)d_in[2];
    const float* w3 = (const float*)d_in[3];
    float* out = (float*)d_out;

    const int blocks = NROWS * NCHUNK;                 // 5376 one-wave blocks
    splitconv_fused_kernel<<<blocks, 64, 0, stream>>>(x, w1, w2, w3, out);
}